// Round 1
// baseline (2140.511 us; speedup 1.0000x reference)
//
#include <hip/hip_runtime.h>

#define FD 128          // feature dim
#define ROWS_PER_BLOCK 4

// ---------------- CSR build ----------------

__global__ void zero_i32(int* __restrict__ p, int n) {
  int i = blockIdx.x * blockDim.x + threadIdx.x;
  if (i < n) p[i] = 0;
}

__global__ void hist_kernel(const int* __restrict__ rows, int* __restrict__ cnt, int nnz) {
  int i = blockIdx.x * blockDim.x + threadIdx.x;
  if (i < nnz) atomicAdd(&cnt[rows[i]], 1);
}

// single-block scan: row_ptr[0]=0, row_ptr[i+1]=sum(cnt[0..i])
__global__ void scan_kernel(const int* __restrict__ cnt, int* __restrict__ row_ptr, int n) {
  __shared__ int sm[1024];
  const int tid = threadIdx.x;
  int carry = 0;
  for (int base = 0; base < n; base += 1024) {
    int i = base + tid;
    int v = (i < n) ? cnt[i] : 0;
    sm[tid] = v;
    __syncthreads();
    for (int off = 1; off < 1024; off <<= 1) {
      int t = (tid >= off) ? sm[tid - off] : 0;
      __syncthreads();
      sm[tid] += t;
      __syncthreads();
    }
    if (i < n) row_ptr[i + 1] = sm[tid] + carry;
    carry += sm[1023];
    __syncthreads();
  }
  if (tid == 0) row_ptr[0] = 0;
}

__global__ void copy_i32(const int* __restrict__ src, int* __restrict__ dst, int n) {
  int i = blockIdx.x * blockDim.x + threadIdx.x;
  if (i < n) dst[i] = src[i];
}

__global__ void scatter_kernel(const int* __restrict__ rows, const int* __restrict__ cols,
                               const float* __restrict__ vals, int* __restrict__ fill,
                               int* __restrict__ cols_s, float* __restrict__ vals_s, int nnz) {
  int i = blockIdx.x * blockDim.x + threadIdx.x;
  if (i < nnz) {
    int r = rows[i];
    int pos = atomicAdd(&fill[r], 1);
    cols_s[pos] = cols[i];
    vals_s[pos] = vals[i];
  }
}

// ---------------- SpMM ----------------
// One wave (64 lanes) per row; each lane owns a float2 (2 features) -> 128 features.
// Gather of Tsrc[c, :] is one coalesced 512B sweep per edge.

__device__ __forceinline__ float2 gather_row_sum(const int* __restrict__ row_ptr,
                                                 const int* __restrict__ cols,
                                                 const float* __restrict__ vals,
                                                 const float* __restrict__ Tsrc,
                                                 int r, int lane) {
  int e = row_ptr[r];
  const int end = row_ptr[r + 1];
  float2 s0 = make_float2(0.f, 0.f);
  float2 s1 = make_float2(0.f, 0.f);
  for (; e + 3 < end; e += 4) {
    int c0 = cols[e + 0], c1 = cols[e + 1], c2 = cols[e + 2], c3 = cols[e + 3];
    float v0 = vals[e + 0], v1 = vals[e + 1], v2 = vals[e + 2], v3 = vals[e + 3];
    float2 x0 = ((const float2*)(Tsrc + (size_t)c0 * FD))[lane];
    float2 x1 = ((const float2*)(Tsrc + (size_t)c1 * FD))[lane];
    float2 x2 = ((const float2*)(Tsrc + (size_t)c2 * FD))[lane];
    float2 x3 = ((const float2*)(Tsrc + (size_t)c3 * FD))[lane];
    s0.x = fmaf(v0, x0.x, s0.x); s0.y = fmaf(v0, x0.y, s0.y);
    s1.x = fmaf(v1, x1.x, s1.x); s1.y = fmaf(v1, x1.y, s1.y);
    s0.x = fmaf(v2, x2.x, s0.x); s0.y = fmaf(v2, x2.y, s0.y);
    s1.x = fmaf(v3, x3.x, s1.x); s1.y = fmaf(v3, x3.y, s1.y);
  }
  for (; e < end; ++e) {
    int c = cols[e];
    float v = vals[e];
    float2 x = ((const float2*)(Tsrc + (size_t)c * FD))[lane];
    s0.x = fmaf(v, x.x, s0.x); s0.y = fmaf(v, x.y, s0.y);
  }
  return make_float2(s0.x + s1.x, s0.y + s1.y);
}

// k=1: T1 = L@X ; acc = c0*X + c1*T1
__global__ void spmm_first(const int* __restrict__ row_ptr, const int* __restrict__ cols,
                           const float* __restrict__ vals, const float* __restrict__ X,
                           float* __restrict__ T1, float* __restrict__ acc,
                           const float* __restrict__ coeffs, int n) {
  const int lane = threadIdx.x & 63;
  const int r = blockIdx.x * ROWS_PER_BLOCK + (threadIdx.x >> 6);
  if (r >= n) return;
  float2 sum = gather_row_sum(row_ptr, cols, vals, X, r, lane);
  const float c0 = coeffs[0], c1 = coeffs[1];
  float2 x0 = ((const float2*)(X + (size_t)r * FD))[lane];
  ((float2*)(T1 + (size_t)r * FD))[lane] = sum;
  float2 a;
  a.x = fmaf(c1, sum.x, c0 * x0.x);
  a.y = fmaf(c1, sum.y, c0 * x0.y);
  ((float2*)(acc + (size_t)r * FD))[lane] = a;
}

// k>=2: Tk = 2*(L@Tsrc) - Tprev ; acc += ck*Tk ; Tk stored to Tdst
// (Tprev may alias Tdst: same element read-then-written by the same thread.)
__global__ void spmm_step(const int* __restrict__ row_ptr, const int* __restrict__ cols,
                          const float* __restrict__ vals, const float* __restrict__ Tsrc,
                          const float* Tprev, float* Tdst, float* __restrict__ acc,
                          const float* __restrict__ coeffs, int k, int n) {
  const int lane = threadIdx.x & 63;
  const int r = blockIdx.x * ROWS_PER_BLOCK + (threadIdx.x >> 6);
  if (r >= n) return;
  float2 sum = gather_row_sum(row_ptr, cols, vals, Tsrc, r, lane);
  const float ck = coeffs[k];
  float2 p = ((const float2*)(Tprev + (size_t)r * FD))[lane];
  float2 t;
  t.x = fmaf(2.f, sum.x, -p.x);
  t.y = fmaf(2.f, sum.y, -p.y);
  ((float2*)(Tdst + (size_t)r * FD))[lane] = t;
  float2 a = ((float2*)(acc + (size_t)r * FD))[lane];
  a.x = fmaf(ck, t.x, a.x);
  a.y = fmaf(ck, t.y, a.y);
  ((float2*)(acc + (size_t)r * FD))[lane] = a;
}

// ---------------- launch ----------------

extern "C" void kernel_launch(void* const* d_in, const int* in_sizes, int n_in,
                              void* d_out, int out_size, void* d_ws, size_t ws_size,
                              hipStream_t stream) {
  const int* rows = (const int*)d_in[0];
  const int* cols = (const int*)d_in[1];
  const float* vals = (const float*)d_in[2];
  const float* X = (const float*)d_in[3];
  const float* coeffs = (const float*)d_in[4];
  float* acc = (float*)d_out;

  const int nnz = in_sizes[0];
  const int n = in_sizes[3] / FD;
  const int M = in_sizes[4];

  // workspace layout (256B-aligned)
  auto align_up = [](size_t x) { return (x + 255) & ~(size_t)255; };
  char* w = (char*)d_ws;
  size_t off = 0;
  int* row_ptr = (int*)(w + off); off = align_up(off + (size_t)(n + 1) * 4);
  int* row_fill = (int*)(w + off); off = align_up(off + (size_t)n * 4);
  int* cols_s = (int*)(w + off); off = align_up(off + (size_t)nnz * 4);
  float* vals_s = (float*)(w + off); off = align_up(off + (size_t)nnz * 4);
  float* buf0 = (float*)(w + off); off = align_up(off + (size_t)n * FD * 4);
  float* buf1 = (float*)(w + off); off = align_up(off + (size_t)n * FD * 4);
  (void)ws_size;

  const int B = 256;
  const int gN = (n + B - 1) / B;
  const int gE = (nnz + B - 1) / B;
  const int gS = (n + ROWS_PER_BLOCK - 1) / ROWS_PER_BLOCK;

  // CSR build (every call — workspace is re-poisoned)
  zero_i32<<<gN, B, 0, stream>>>(row_fill, n);
  hist_kernel<<<gE, B, 0, stream>>>(rows, row_fill, nnz);
  scan_kernel<<<1, 1024, 0, stream>>>(row_fill, row_ptr, n);
  copy_i32<<<gN, B, 0, stream>>>(row_ptr, row_fill, n);
  scatter_kernel<<<gE, B, 0, stream>>>(rows, cols, vals, row_fill, cols_s, vals_s, nnz);

  // k = 1
  spmm_first<<<gS, B, 0, stream>>>(row_ptr, cols_s, vals_s, X, buf0, acc, coeffs, n);
  // k = 2: prev = X (read-only input), dst = buf1
  if (M > 2)
    spmm_step<<<gS, B, 0, stream>>>(row_ptr, cols_s, vals_s, buf0, X, buf1, acc, coeffs, 2, n);
  // k >= 3: src = bufs[k&1], prev = dst = bufs[(k+1)&1] (in-place)
  for (int k = 3; k < M; ++k) {
    float* src = (k & 1) ? buf1 : buf0;
    float* pd  = (k & 1) ? buf0 : buf1;
    spmm_step<<<gS, B, 0, stream>>>(row_ptr, cols_s, vals_s, src, pd, pd, acc, coeffs, k, n);
  }
}